// Round 6
// baseline (164.862 us; speedup 1.0000x reference)
//
#include <hip/hip_runtime.h>
#include <hip/hip_bf16.h>

#define N_NODES 50000
#define N_EDGES 640000
#define N_REL   200
#define D       128
#define CAP     64              // bucket capacity; max degree ~35 (Poisson 12.8)
#define RANGES  8               // one target-range per XCD
#define NODES_PER_RANGE (N_NODES / RANGES)   // 6250
#define CHUNK_EDGES 2560
#define N_CHUNKS (N_EDGES / CHUNK_EDGES)     // 250

// prep_kernel block ranges
#define SN_BLOCKS   6250                     // 8 nodes/block, half-wave each
#define SREL_BLOCKS 50
#define CNT_BLOCKS  196
#define PREP_BLOCKS (SN_BLOCKS + SREL_BLOCKS + CNT_BLOCKS)

// fused kernel geometry: interleave xtrans and scatter at 8-block granularity
// so scatter keeps blockIdx&7 == target-range == XCD (round-robin mapping).
#define XT_WAVES   (N_NODES / 16)            // 3125 MFMA waves
#define XT_BLOCKS  782                       // ceil(3125/4)
#define XT_GROUPS  98                        // ceil(782/8)
#define SC_GROUPS  N_CHUNKS                  // 250
#define TOT_GROUPS (XT_GROUPS + SC_GROUPS)   // 348 -> grid 2784 blocks

// gather geometry: 4 nodes per wave, XCD-matched (blockIdx&7 == range)
#define G_BLOCKS_PER_RANGE 391               // ceil(6250/16)

typedef __attribute__((ext_vector_type(8))) short short8;   // 8 bf16 (4 VGPRs)
typedef __attribute__((ext_vector_type(4))) float floatx4;  // MFMA acc / f32x4
typedef __attribute__((ext_vector_type(4))) unsigned uintx4;

__device__ __forceinline__ unsigned short f2bf(float f) {   // RNE f32->bf16
    unsigned u = __float_as_uint(f);
    u += 0x7FFF + ((u >> 16) & 1);
    return (unsigned short)(u >> 16);
}

__device__ __forceinline__ float sigmoidf(float x) {
    return 1.f / (1.f + __expf(-x));
}

// ---------------------------------------------------------------------------
// Kernel 1 (prep, ~6 us, BW-bound): everything scatter depends on.
//   blocks 0..6249    : s_node[n] = dot(x[n], W_attn), half-wave per node
//   blocks 6250..6299 : s_rel[r] = dot(rel_emb[r], W_attn)
//   blocks 6300..6495 : zero count[]
// ---------------------------------------------------------------------------
__global__ __launch_bounds__(256) void prep_kernel(
        const float* __restrict__ x,
        const float* __restrict__ rel,
        const float* __restrict__ Wattn,
        float* __restrict__ s_node,
        float* __restrict__ s_rel,
        int* __restrict__ count) {
    const int b = blockIdx.x;
    if (b < SN_BLOCKS) {
        const int node = b * 8 + (threadIdx.x >> 5);
        const int sub  = threadIdx.x & 31;
        if (node < N_NODES) {
            const float4 xv = ((const float4*)(x + (size_t)node * D))[sub];
            const float4 wv = ((const float4*)Wattn)[sub];
            float a = xv.x * wv.x + xv.y * wv.y + xv.z * wv.z + xv.w * wv.w;
#pragma unroll
            for (int off = 16; off; off >>= 1)
                a += __shfl_xor(a, off);              // within 32-lane half
            if (sub == 0) s_node[node] = a;
        }
    } else if (b < SN_BLOCKS + SREL_BLOCKS) {
        const int wave = (b - SN_BLOCKS) * 4 + (threadIdx.x >> 6);
        const int lane = threadIdx.x & 63;
        if (wave < N_REL) {
            const float* __restrict__ row = rel + (size_t)wave * D;
            float a = fmaf(row[lane], Wattn[lane],
                           row[lane + 64] * Wattn[lane + 64]);
#pragma unroll
            for (int off = 32; off; off >>= 1)
                a += __shfl_down(a, off);
            if (lane == 0) s_rel[wave] = a;
        }
    } else {
        const int i = (b - SN_BLOCKS - SREL_BLOCKS) * 256 + threadIdx.x;
        if (i < N_NODES) count[i] = 0;
    }
}

// ---------------------------------------------------------------------------
// Kernel 2 (FUSED): xtrans (MFMA) || scatter -- independent given s_node.
// R1 retry with both poisons fixed:
//   - edge loads CACHED (8 range-blocks of a chunk are blockIdx-adjacent ->
//     land on 8 XCDs nearly together -> L3 serves 7/8 re-reads; R1's NT hint
//     defeated this: FETCH 43.3 vs 33 MB expected)
//   - x loads / xt stores NONTEMPORAL (early-evict) so the xtrans stream
//     cannot displace the XCD-local dirty sorted/count slices (R1: WRITE_SIZE
//     38.8 vs 18 MB expected). xt is L3-bound for gather anyway (12.8 MB).
// Bresenham over 348 groups of 8 blocks: scatter block keeps range == b&7.
// NT loads go through ext_vector floatx4 (clang builtin rejects HIP float4).
// ---------------------------------------------------------------------------
__global__ __launch_bounds__(256) void fused_kernel(
        const float* __restrict__ x,
        const float* __restrict__ W,
        unsigned short* __restrict__ xt,
        const int* __restrict__ src_idx,
        const int* __restrict__ tgt_idx,
        const int* __restrict__ etype,
        const float* __restrict__ s_node,
        const float* __restrict__ s_rel,
        int* __restrict__ count,
        unsigned* __restrict__ sorted) {
    __shared__ unsigned short lw[D * D];      // 32 KB swizzled bf16 W
    __shared__ float ls_rel[N_REL];

    const int g    = blockIdx.x >> 3;
    const int sub8 = blockIdx.x & 7;
    const int xg   = (g * XT_GROUPS) / TOT_GROUPS;                 // x-groups before g
    const bool is_x = (((g + 1) * XT_GROUPS) / TOT_GROUPS) > xg;

    if (is_x) {
        // ---- stage W into swizzled LDS (all 256 threads; cached loads) ----
        const int tid = threadIdx.x;
#pragma unroll
        for (int i = 0; i < 8; ++i) {
            const int idx8 = tid + i * 256;           // 8-element group id
            const int row  = idx8 >> 4;               // 0..127
            const int kk   = idx8 & 15;               // k0/8
            const float* __restrict__ wr = W + (size_t)row * D + kk * 8;
            const float4 lo = *(const float4*)(wr);
            const float4 hi = *(const float4*)(wr + 4);
            short8 v;
            v[0] = (short)f2bf(lo.x); v[1] = (short)f2bf(lo.y);
            v[2] = (short)f2bf(lo.z); v[3] = (short)f2bf(lo.w);
            v[4] = (short)f2bf(hi.x); v[5] = (short)f2bf(hi.y);
            v[6] = (short)f2bf(hi.z); v[7] = (short)f2bf(hi.w);
            const int slot = (row * 16 + kk) ^ (row & 7);
            *(short8*)((char*)lw + slot * 16) = v;
        }
        __syncthreads();

        const int wid = (xg * 8 + sub8) * 4 + (threadIdx.x >> 6);
        if (wid >= XT_WAVES) return;               // tail waves idle (post-barrier)
        const int lane = threadIdx.x & 63;
        const int r16  = lane & 15;
        const int quad = lane >> 4;
        const int m0   = wid * 16;

        short8 af[4];
#pragma unroll
        for (int s = 0; s < 4; ++s) {
            const int k0 = s * 32 + quad * 8;
            const float* __restrict__ xr = x + (size_t)(m0 + r16) * D + k0;
            const floatx4 lo = __builtin_nontemporal_load((const floatx4*)(xr));
            const floatx4 hi = __builtin_nontemporal_load((const floatx4*)(xr + 4));
            short8 a;
            a[0] = (short)f2bf(lo[0]); a[1] = (short)f2bf(lo[1]);
            a[2] = (short)f2bf(lo[2]); a[3] = (short)f2bf(lo[3]);
            a[4] = (short)f2bf(hi[0]); a[5] = (short)f2bf(hi[1]);
            a[6] = (short)f2bf(hi[2]); a[7] = (short)f2bf(hi[3]);
            af[s] = a;
        }

#pragma unroll
        for (int t = 0; t < 8; ++t) {
            floatx4 acc = {0.f, 0.f, 0.f, 0.f};
            const int row = t * 16 + r16;
#pragma unroll
            for (int s = 0; s < 4; ++s) {
                const int slot = (row * 16 + s * 4 + quad) ^ (row & 7);
                const short8 bfrag = *(const short8*)((const char*)lw + slot * 16);
                acc = __builtin_amdgcn_mfma_f32_16x16x32_bf16(af[s], bfrag, acc, 0, 0, 0);
            }
#pragma unroll
            for (int r = 0; r < 4; ++r) {
                const int orow = m0 + quad * 4 + r;
                __builtin_nontemporal_store(f2bf(acc[r]),
                    xt + (size_t)orow * D + t * 16 + r16);
            }
        }
    } else {
        // ---- scatter: chunk sg, target range sub8 (XCD-local L2 writes) ----
        if (threadIdx.x < N_REL) ls_rel[threadIdx.x] = s_rel[threadIdx.x];
        __syncthreads();

        const int sg   = g - xg;                    // 0..249
        const int lo   = sub8 * NODES_PER_RANGE;
        const int hi   = lo + NODES_PER_RANGE;
        const int base = sg * CHUNK_EDGES + threadIdx.x;

#pragma unroll
        for (int it = 0; it < CHUNK_EDGES / 256; ++it) {
            const int e = base + it * 256;
            const int t = tgt_idx[e];                // coalesced, cached
            const int s = src_idx[e];                // coalesced, unconditional
            const int r = etype[e];                  // coalesced, unconditional
            if (t >= lo && t < hi) {
                const float logit = s_node[s] + ls_rel[r];
                const unsigned rec =
                    ((unsigned)f2bf(sigmoidf(logit)) << 16) | (unsigned)s;
                const int k = atomicAdd(&count[t], 1);
                sorted[t * CAP + k] = rec;           // XCD-local L2 write
            }
        }
    }
}

// ---------------------------------------------------------------------------
// Kernel 3: gather + fused ReLU. FOUR nodes per wave (16 lanes each, uint4 =
// 16B/lane). XCD-matched: blockIdx&7 == node range == the XCD whose scatter
// wrote these count/sorted lines.
// ---------------------------------------------------------------------------
__device__ __forceinline__ void gproc4(unsigned r, const unsigned short* __restrict__ xt,
                                       int sub, floatx4& a0, floatx4& a1) {
    const unsigned src = r & 0xFFFFu;
    const float a = __uint_as_float(r & 0xFFFF0000u);
    const uint4 p = *(const uint4*)(xt + (size_t)src * D + sub * 8);
    a0[0] = fmaf(a, __uint_as_float(p.x << 16),         a0[0]);
    a0[1] = fmaf(a, __uint_as_float(p.x & 0xFFFF0000u), a0[1]);
    a0[2] = fmaf(a, __uint_as_float(p.y << 16),         a0[2]);
    a0[3] = fmaf(a, __uint_as_float(p.y & 0xFFFF0000u), a0[3]);
    a1[0] = fmaf(a, __uint_as_float(p.z << 16),         a1[0]);
    a1[1] = fmaf(a, __uint_as_float(p.z & 0xFFFF0000u), a1[1]);
    a1[2] = fmaf(a, __uint_as_float(p.w << 16),         a1[2]);
    a1[3] = fmaf(a, __uint_as_float(p.w & 0xFFFF0000u), a1[3]);
}

__global__ __launch_bounds__(256) void gather_kernel(
        const int* __restrict__ count,
        const unsigned* __restrict__ sorted,
        const unsigned short* __restrict__ xt,
        float* __restrict__ out) {
    const int rng   = blockIdx.x & 7;
    const int idx   = blockIdx.x >> 3;               // 0..390
    const int w     = threadIdx.x >> 6;
    const int lane  = threadIdx.x & 63;
    const int q     = lane >> 4;
    const int sub   = lane & 15;
    const int local = idx * 16 + w * 4 + q;
    if (local >= NODES_PER_RANGE) return;
    const int t = rng * NODES_PER_RANGE + local;

    const int cnt = count[t];
    const unsigned* __restrict__ rec = sorted + (size_t)t * CAP;

    floatx4 a0 = {0.f, 0.f, 0.f, 0.f};
    floatx4 a1 = {0.f, 0.f, 0.f, 0.f};
    int i = 0;
    for (; i + 4 <= cnt; i += 4) {
        const uintx4 r4 = __builtin_nontemporal_load((const uintx4*)(rec + i));
        gproc4(r4.x, xt, sub, a0, a1);
        gproc4(r4.y, xt, sub, a0, a1);
        gproc4(r4.z, xt, sub, a0, a1);
        gproc4(r4.w, xt, sub, a0, a1);
    }
    for (; i < cnt; ++i)
        gproc4(__builtin_nontemporal_load(rec + i), xt, sub, a0, a1);

    floatx4 o0, o1;
    o0[0] = fmaxf(a0[0], 0.f); o0[1] = fmaxf(a0[1], 0.f);
    o0[2] = fmaxf(a0[2], 0.f); o0[3] = fmaxf(a0[3], 0.f);
    o1[0] = fmaxf(a1[0], 0.f); o1[1] = fmaxf(a1[1], 0.f);
    o1[2] = fmaxf(a1[2], 0.f); o1[3] = fmaxf(a1[3], 0.f);
    floatx4* orow = (floatx4*)(out + (size_t)t * D) + sub * 2;
    __builtin_nontemporal_store(o0, orow);
    __builtin_nontemporal_store(o1, orow + 1);
}

extern "C" void kernel_launch(void* const* d_in, const int* in_sizes, int n_in,
                              void* d_out, int out_size, void* d_ws, size_t ws_size,
                              hipStream_t stream) {
    const float* x        = (const float*)d_in[0];              // [N, 128]
    const int*   edge_idx = (const int*)d_in[1];                // [2, E]
    const int*   etype    = (const int*)d_in[2];                // [E]
    const float* rel_emb  = (const float*)d_in[3];              // [R, 128]
    const float* W_lin    = (const float*)d_in[4];              // [128, 128]
    const float* W_attn   = (const float*)d_in[5];              // [1, 128]
    float* out = (float*)d_out;                                 // [N, 128]

    const int* src_idx = edge_idx;
    const int* tgt_idx = edge_idx + N_EDGES;

    // workspace layout (~26 MB total)
    unsigned short* xt   = (unsigned short*)d_ws;               // 12.8 MB (bf16)
    float* s_node        = (float*)(xt + (size_t)N_NODES * D);  // 200 KB
    float* s_rel         = s_node + N_NODES;                    // 800 B
    int*   count         = (int*)(s_rel + N_REL);               // 200 KB
    unsigned* sorted     = (unsigned*)(count + N_NODES);        // 12.8 MB

    // 1. prep: s_node + s_rel + count-zero (everything scatter needs)
    prep_kernel<<<dim3(PREP_BLOCKS), dim3(256), 0, stream>>>(
        x, rel_emb, W_attn, s_node, s_rel, count);

    // 2. FUSED xtrans (MFMA, NT streams) || scatter (cached edges, L2-local)
    fused_kernel<<<dim3(TOT_GROUPS * 8), dim3(256), 0, stream>>>(
        x, W_lin, xt, src_idx, tgt_idx, etype, s_node, s_rel, count, sorted);

    // 3. gather + fused ReLU (4 nodes per wave, XCD-matched)
    gather_kernel<<<dim3(G_BLOCKS_PER_RANGE * RANGES), dim3(256), 0, stream>>>(
        count, sorted, xt, out);
}

// Round 7
// 157.902 us; speedup vs baseline: 1.0441x; 1.0441x over previous
//
#include <hip/hip_runtime.h>
#include <hip/hip_bf16.h>

#define N_NODES 50000
#define N_EDGES 640000
#define N_REL   200
#define D       128
#define CAP     64              // bucket capacity; max degree ~35 (Poisson 12.8)
#define RANGES  8               // one target-range per XCD
#define NODES_PER_RANGE (N_NODES / RANGES)   // 6250
#define CHUNK_EDGES 2560
#define N_CHUNKS (N_EDGES / CHUNK_EDGES)     // 250

// pre_kernel geometry: 2 half-col waves per 16-node group (2x TLP vs R4)
#define XT_NG      3125                      // 16-node groups
#define XT_WAVES2  (XT_NG * 2)               // 6250 split waves
#define XT_BLOCKS  1563                      // ceil(6250/4)
#define SREL_BLOCKS 50
#define CNT_BLOCKS 196
#define PRE_BLOCKS (XT_BLOCKS + SREL_BLOCKS + CNT_BLOCKS)

// gather geometry: 4 nodes per wave, XCD-matched (blockIdx&7 == range)
#define G_BLOCKS_PER_RANGE 391               // ceil(6250/16)

typedef __attribute__((ext_vector_type(8))) short short8;   // 8 bf16 (4 VGPRs)
typedef __attribute__((ext_vector_type(4))) float floatx4;  // MFMA acc / f32x4
typedef __attribute__((ext_vector_type(4))) unsigned uintx4;

__device__ __forceinline__ unsigned short f2bf(float f) {   // RNE f32->bf16
    unsigned u = __float_as_uint(f);
    u += 0x7FFF + ((u >> 16) & 1);
    return (unsigned short)(u >> 16);
}

__device__ __forceinline__ float sigmoidf(float x) {
    return 1.f / (1.f + __expf(-x));
}

// ---------------------------------------------------------------------------
// Kernel 1 (pre): everything before scatter. R4 structure, 2x wave split.
//   blocks 0..1562    : xtrans via MFMA, W f32->bf16 in swizzled LDS.
//                       TWO waves per 16-node group (cols 0..63 / 64..127):
//                       6250 waves (~6/SIMD) halve the per-wave chain that
//                       left R4's 3125 waves (~3/SIMD) latency-exposed.
//                       s_node fused into the half-0 wave (x read once).
//   blocks 1563..1612 : s_rel[r] = dot(rel_emb[r], W_attn)
//   blocks 1613..1808 : zero count[]
// ---------------------------------------------------------------------------
__global__ __launch_bounds__(256) void pre_kernel(
        const float* __restrict__ x,
        const float* __restrict__ W,
        const float* __restrict__ rel,
        const float* __restrict__ Wattn,
        unsigned short* __restrict__ xt,
        float* __restrict__ s_node,
        float* __restrict__ s_rel,
        int* __restrict__ count) {
    __shared__ unsigned short lw[D * D];      // 32 KB swizzled bf16 W
    const int b = blockIdx.x;

    if (b < XT_BLOCKS) {
        // ---- stage W into swizzled LDS (all 256 threads) ----
        const int tid = threadIdx.x;
#pragma unroll
        for (int i = 0; i < 8; ++i) {
            const int idx8 = tid + i * 256;           // 8-element group id
            const int row  = idx8 >> 4;               // 0..127
            const int kk   = idx8 & 15;               // k0/8
            const float* __restrict__ wr = W + (size_t)row * D + kk * 8;
            const float4 lo = *(const float4*)(wr);
            const float4 hi = *(const float4*)(wr + 4);
            short8 v;
            v[0] = (short)f2bf(lo.x); v[1] = (short)f2bf(lo.y);
            v[2] = (short)f2bf(lo.z); v[3] = (short)f2bf(lo.w);
            v[4] = (short)f2bf(hi.x); v[5] = (short)f2bf(hi.y);
            v[6] = (short)f2bf(hi.z); v[7] = (short)f2bf(hi.w);
            const int slot = (row * 16 + kk) ^ (row & 7);
            *(short8*)((char*)lw + slot * 16) = v;
        }
        __syncthreads();

        const int wv = b * 4 + (threadIdx.x >> 6);    // 0..6251
        if (wv >= XT_WAVES2) return;                  // last 2 waves idle
        const int ng   = wv >> 1;                     // 16-node group
        const int hf   = wv & 1;                      // column half
        const int lane = threadIdx.x & 63;
        const int r16  = lane & 15;
        const int quad = lane >> 4;
        const int m0   = ng * 16;

        short8 af[4];
        float  sn = 0.f;                              // dot(x[row], W_attn)
#pragma unroll
        for (int s = 0; s < 4; ++s) {
            const int k0 = s * 32 + quad * 8;
            const float* __restrict__ xr = x + (size_t)(m0 + r16) * D + k0;
            const float4 lo = *(const float4*)(xr);
            const float4 hi = *(const float4*)(xr + 4);
            if (hf == 0) {                            // wave-uniform branch
                const float4 wl = *(const float4*)(Wattn + k0);
                const float4 wh = *(const float4*)(Wattn + k0 + 4);
                sn = fmaf(lo.x, wl.x, sn); sn = fmaf(lo.y, wl.y, sn);
                sn = fmaf(lo.z, wl.z, sn); sn = fmaf(lo.w, wl.w, sn);
                sn = fmaf(hi.x, wh.x, sn); sn = fmaf(hi.y, wh.y, sn);
                sn = fmaf(hi.z, wh.z, sn); sn = fmaf(hi.w, wh.w, sn);
            }
            short8 a;
            a[0] = (short)f2bf(lo.x); a[1] = (short)f2bf(lo.y);
            a[2] = (short)f2bf(lo.z); a[3] = (short)f2bf(lo.w);
            a[4] = (short)f2bf(hi.x); a[5] = (short)f2bf(hi.y);
            a[6] = (short)f2bf(hi.z); a[7] = (short)f2bf(hi.w);
            af[s] = a;
        }
        if (hf == 0) {
            sn += __shfl_xor(sn, 16);
            sn += __shfl_xor(sn, 32);
            if (lane < 16) s_node[m0 + r16] = sn;    // 64B coalesced per wave
        }

#pragma unroll
        for (int t = 0; t < 4; ++t) {
            const int tt = hf * 4 + t;
            floatx4 acc = {0.f, 0.f, 0.f, 0.f};
            const int row = tt * 16 + r16;
#pragma unroll
            for (int s = 0; s < 4; ++s) {
                const int slot = (row * 16 + s * 4 + quad) ^ (row & 7);
                const short8 bfrag = *(const short8*)((const char*)lw + slot * 16);
                acc = __builtin_amdgcn_mfma_f32_16x16x32_bf16(af[s], bfrag, acc, 0, 0, 0);
            }
#pragma unroll
            for (int r = 0; r < 4; ++r) {
                const int orow = m0 + quad * 4 + r;
                xt[(size_t)orow * D + tt * 16 + r16] = f2bf(acc[r]);
            }
        }
    } else if (b < XT_BLOCKS + SREL_BLOCKS) {
        const int wave = (b - XT_BLOCKS) * 4 + (threadIdx.x >> 6);
        const int lane = threadIdx.x & 63;
        if (wave < N_REL) {
            const float* __restrict__ row = rel + (size_t)wave * D;
            float a = fmaf(row[lane], Wattn[lane],
                           row[lane + 64] * Wattn[lane + 64]);
#pragma unroll
            for (int off = 32; off; off >>= 1)
                a += __shfl_down(a, off);
            if (lane == 0) s_rel[wave] = a;
        }
    } else {
        const int i = (b - XT_BLOCKS - SREL_BLOCKS) * 256 + threadIdx.x;
        if (i < N_NODES) count[i] = 0;
    }
}

// ---------------------------------------------------------------------------
// Kernel 2: XCD-partitioned bucket scatter (R4-exact: proven; fusion with any
// streaming stage evicts the L2-resident sorted/count slices -- refuted 2x).
// ---------------------------------------------------------------------------
__global__ __launch_bounds__(256) void scatter_kernel(
        const int* __restrict__ src_idx,
        const int* __restrict__ tgt_idx,
        const int* __restrict__ etype,
        const float* __restrict__ s_node,
        const float* __restrict__ s_rel,
        int* __restrict__ count,
        unsigned* __restrict__ sorted) {
    __shared__ float ls_rel[N_REL];
    if (threadIdx.x < N_REL) ls_rel[threadIdx.x] = s_rel[threadIdx.x];
    __syncthreads();

    const int b     = blockIdx.x;
    const int lo    = (b & 7) * NODES_PER_RANGE;
    const int hi    = lo + NODES_PER_RANGE;
    const int base  = (b >> 3) * CHUNK_EDGES + threadIdx.x;

#pragma unroll
    for (int it = 0; it < CHUNK_EDGES / 256; ++it) {
        const int e = base + it * 256;
        const int t = tgt_idx[e];                    // coalesced, cached
        const int s = src_idx[e];                    // coalesced, unconditional
        const int r = etype[e];                      // coalesced, unconditional
        if (t >= lo && t < hi) {
            const float logit = s_node[s] + ls_rel[r];
            const unsigned rec =
                ((unsigned)f2bf(sigmoidf(logit)) << 16) | (unsigned)s;
            const int k = atomicAdd(&count[t], 1);
            sorted[t * CAP + k] = rec;               // XCD-local L2 write
        }
    }
}

// ---------------------------------------------------------------------------
// Kernel 3: gather + fused ReLU. FOUR nodes per wave (16 lanes each, uint4 =
// 16B/lane). 8-record batches: 8 independent xt-row loads in flight per
// round -> serial rounds per node ~halved (avg cnt 12.8: 4 -> ~2).
// XCD-matched: blockIdx&7 == node range == the XCD whose scatter wrote
// these count/sorted lines.
// ---------------------------------------------------------------------------
__device__ __forceinline__ void gproc4(unsigned r, const unsigned short* __restrict__ xt,
                                       int sub, floatx4& a0, floatx4& a1) {
    const unsigned src = r & 0xFFFFu;
    const float a = __uint_as_float(r & 0xFFFF0000u);
    const uint4 p = *(const uint4*)(xt + (size_t)src * D + sub * 8);
    a0[0] = fmaf(a, __uint_as_float(p.x << 16),         a0[0]);
    a0[1] = fmaf(a, __uint_as_float(p.x & 0xFFFF0000u), a0[1]);
    a0[2] = fmaf(a, __uint_as_float(p.y << 16),         a0[2]);
    a0[3] = fmaf(a, __uint_as_float(p.y & 0xFFFF0000u), a0[3]);
    a1[0] = fmaf(a, __uint_as_float(p.z << 16),         a1[0]);
    a1[1] = fmaf(a, __uint_as_float(p.z & 0xFFFF0000u), a1[1]);
    a1[2] = fmaf(a, __uint_as_float(p.w << 16),         a1[2]);
    a1[3] = fmaf(a, __uint_as_float(p.w & 0xFFFF0000u), a1[3]);
}

__global__ __launch_bounds__(256) void gather_kernel(
        const int* __restrict__ count,
        const unsigned* __restrict__ sorted,
        const unsigned short* __restrict__ xt,
        float* __restrict__ out) {
    const int rng   = blockIdx.x & 7;
    const int idx   = blockIdx.x >> 3;               // 0..390
    const int w     = threadIdx.x >> 6;
    const int lane  = threadIdx.x & 63;
    const int q     = lane >> 4;
    const int sub   = lane & 15;
    const int local = idx * 16 + w * 4 + q;
    if (local >= NODES_PER_RANGE) return;
    const int t = rng * NODES_PER_RANGE + local;

    const int cnt = count[t];
    const unsigned* __restrict__ rec = sorted + (size_t)t * CAP;

    floatx4 a0 = {0.f, 0.f, 0.f, 0.f};
    floatx4 a1 = {0.f, 0.f, 0.f, 0.f};
    int i = 0;
    for (; i + 8 <= cnt; i += 8) {                   // 8 rows in flight
        const uintx4 ra = __builtin_nontemporal_load((const uintx4*)(rec + i));
        const uintx4 rb = __builtin_nontemporal_load((const uintx4*)(rec + i + 4));
        gproc4(ra.x, xt, sub, a0, a1);
        gproc4(ra.y, xt, sub, a0, a1);
        gproc4(ra.z, xt, sub, a0, a1);
        gproc4(ra.w, xt, sub, a0, a1);
        gproc4(rb.x, xt, sub, a0, a1);
        gproc4(rb.y, xt, sub, a0, a1);
        gproc4(rb.z, xt, sub, a0, a1);
        gproc4(rb.w, xt, sub, a0, a1);
    }
    for (; i + 4 <= cnt; i += 4) {
        const uintx4 r4 = __builtin_nontemporal_load((const uintx4*)(rec + i));
        gproc4(r4.x, xt, sub, a0, a1);
        gproc4(r4.y, xt, sub, a0, a1);
        gproc4(r4.z, xt, sub, a0, a1);
        gproc4(r4.w, xt, sub, a0, a1);
    }
    for (; i < cnt; ++i)
        gproc4(__builtin_nontemporal_load(rec + i), xt, sub, a0, a1);

    floatx4 o0, o1;
    o0[0] = fmaxf(a0[0], 0.f); o0[1] = fmaxf(a0[1], 0.f);
    o0[2] = fmaxf(a0[2], 0.f); o0[3] = fmaxf(a0[3], 0.f);
    o1[0] = fmaxf(a1[0], 0.f); o1[1] = fmaxf(a1[1], 0.f);
    o1[2] = fmaxf(a1[2], 0.f); o1[3] = fmaxf(a1[3], 0.f);
    floatx4* orow = (floatx4*)(out + (size_t)t * D) + sub * 2;
    __builtin_nontemporal_store(o0, orow);
    __builtin_nontemporal_store(o1, orow + 1);
}

extern "C" void kernel_launch(void* const* d_in, const int* in_sizes, int n_in,
                              void* d_out, int out_size, void* d_ws, size_t ws_size,
                              hipStream_t stream) {
    const float* x        = (const float*)d_in[0];              // [N, 128]
    const int*   edge_idx = (const int*)d_in[1];                // [2, E]
    const int*   etype    = (const int*)d_in[2];                // [E]
    const float* rel_emb  = (const float*)d_in[3];              // [R, 128]
    const float* W_lin    = (const float*)d_in[4];              // [128, 128]
    const float* W_attn   = (const float*)d_in[5];              // [1, 128]
    float* out = (float*)d_out;                                 // [N, 128]

    const int* src_idx = edge_idx;
    const int* tgt_idx = edge_idx + N_EDGES;

    // workspace layout (~26 MB total)
    unsigned short* xt   = (unsigned short*)d_ws;               // 12.8 MB (bf16)
    float* s_node        = (float*)(xt + (size_t)N_NODES * D);  // 200 KB
    float* s_rel         = s_node + N_NODES;                    // 800 B
    int*   count         = (int*)(s_rel + N_REL);               // 200 KB
    unsigned* sorted     = (unsigned*)(count + N_NODES);        // 12.8 MB

    // 1. pre: xtrans(MFMA, 2x split waves) + s_node + s_rel + count-zero
    pre_kernel<<<dim3(PRE_BLOCKS), dim3(256), 0, stream>>>(
        x, W_lin, rel_emb, W_attn, xt, s_node, s_rel, count);

    // 2. XCD-partitioned bucket scatter (2000 blocks = 250 chunks x 8 ranges)
    scatter_kernel<<<dim3(N_CHUNKS * RANGES), dim3(256), 0, stream>>>(
        src_idx, tgt_idx, etype, s_node, s_rel, count, sorted);

    // 3. gather + fused ReLU (4 nodes/wave, 8-rec batches, XCD-matched)
    gather_kernel<<<dim3(G_BLOCKS_PER_RANGE * RANGES), dim3(256), 0, stream>>>(
        count, sorted, xt, out);
}